// Round 3
// baseline (623.346 us; speedup 1.0000x reference)
//
#include <hip/hip_runtime.h>
#include <cstdint>
#include <cstddef>

// Top-1 MoE gate. s=8192, e=64, d=2048, cap=128.
// d_out (float32): [l_aux(1), combine(8192*64*128), mask(8192*64*128)]
// Pipeline: logits (split-K fp32 GEMM, zeroes gsum) -> reduce(+softmax/argmax)
//           -> scan (ranks + pos2/val2 tables + l_aux) -> writer (dense 537MB)

#define S_TOK 8192
#define NEXP 64
#define DIM 2048
#define CAP 128
#define COMB_ELEMS ((size_t)S_TOK * NEXP * CAP)   // 67108864
#define OUT_ELEMS (1 + 2 * COMB_ELEMS)            // 134217729

#define TOK_TILE 128
#define NSLICE 4
#define KSLICE (DIM / NSLICE)   // 512
#define KC 32

// ---------------------------------------------------------------------------
// Kernel 1: split-K logits GEMM. grid = 64 token-tiles x 4 k-slices = 256.
// 256 threads; thread tile 8 tok x 4 exp. Block 0 zeroes gsum (saves a memset).
// ---------------------------------------------------------------------------
__global__ __launch_bounds__(256) void logits_kernel(
    const float* __restrict__ x, const float* __restrict__ wg,
    float* __restrict__ P, float* __restrict__ gsum)
{
    __shared__ float xs[KC][132];
    __shared__ float wsh[KC][68];

    const int tid  = threadIdx.x;
    const int tile  = blockIdx.x >> 2;
    const int slice = blockIdx.x & 3;
    const int tok0 = tile * TOK_TILE;
    const int k0   = slice * KSLICE;

    if (blockIdx.x == 0 && tid < NEXP) gsum[tid] = 0.0f;

    const int tt = tid >> 4;
    const int te = tid & 15;

    float acc[8][4];
#pragma unroll
    for (int i = 0; i < 8; ++i)
#pragma unroll
        for (int j = 0; j < 4; ++j) acc[i][j] = 0.0f;

    const int we  = tid & 63;
    const int wkq = tid >> 6;

    float4 xv[4], wv[2];
#pragma unroll
    for (int r = 0; r < 4; ++r) {
        int idx = tid + 256 * r;
        int t = idx >> 3, kq = idx & 7;
        xv[r] = *(const float4*)(x + (size_t)(tok0 + t) * DIM + k0 + 4 * kq);
    }
    wv[0] = *(const float4*)(wg + (size_t)we * DIM + k0 + 4 * wkq);
    wv[1] = *(const float4*)(wg + (size_t)we * DIM + k0 + 4 * (wkq + 4));

    for (int kc = 0; kc < KSLICE; kc += KC) {
        __syncthreads();
#pragma unroll
        for (int r = 0; r < 4; ++r) {
            int idx = tid + 256 * r;
            int t = idx >> 3, k4 = (idx & 7) * 4;
            xs[k4 + 0][t] = xv[r].x; xs[k4 + 1][t] = xv[r].y;
            xs[k4 + 2][t] = xv[r].z; xs[k4 + 3][t] = xv[r].w;
        }
        {
            int k4 = 4 * wkq;
            wsh[k4 + 0][we] = wv[0].x; wsh[k4 + 1][we] = wv[0].y;
            wsh[k4 + 2][we] = wv[0].z; wsh[k4 + 3][we] = wv[0].w;
            int k4b = k4 + 16;
            wsh[k4b + 0][we] = wv[1].x; wsh[k4b + 1][we] = wv[1].y;
            wsh[k4b + 2][we] = wv[1].z; wsh[k4b + 3][we] = wv[1].w;
        }
        __syncthreads();
        if (kc + KC < KSLICE) {
#pragma unroll
            for (int r = 0; r < 4; ++r) {
                int idx = tid + 256 * r;
                int t = idx >> 3, kq = idx & 7;
                xv[r] = *(const float4*)(x + (size_t)(tok0 + t) * DIM + k0 + kc + KC + 4 * kq);
            }
            wv[0] = *(const float4*)(wg + (size_t)we * DIM + k0 + kc + KC + 4 * wkq);
            wv[1] = *(const float4*)(wg + (size_t)we * DIM + k0 + kc + KC + 4 * (wkq + 4));
        }
#pragma unroll 8
        for (int k = 0; k < KC; ++k) {
            float4 a0 = *(const float4*)&xs[k][8 * tt];
            float4 a1 = *(const float4*)&xs[k][8 * tt + 4];
            float4 b  = *(const float4*)&wsh[k][4 * te];
            const float* ap0 = &a0.x; const float* ap1 = &a1.x; const float* bp = &b.x;
#pragma unroll
            for (int i = 0; i < 4; ++i)
#pragma unroll
                for (int j = 0; j < 4; ++j) {
                    acc[i][j]     += ap0[i] * bp[j];
                    acc[i + 4][j] += ap1[i] * bp[j];
                }
        }
    }

#pragma unroll
    for (int i = 0; i < 8; ++i) {
        size_t off = ((size_t)slice * S_TOK + tok0 + 8 * tt + i) * NEXP + 4 * te;
        float4 v = { acc[i][0], acc[i][1], acc[i][2], acc[i][3] };
        *(float4*)(P + off) = v;
    }
}

// ---------------------------------------------------------------------------
// Kernel 2: reduce 4 partials (fixed order) + softmax + argmax + gate sums.
// ---------------------------------------------------------------------------
__global__ __launch_bounds__(256) void reduce_kernel(
    const float* __restrict__ P,
    int* __restrict__ idx_out, float* __restrict__ gate_out,
    float* __restrict__ gsum)
{
    __shared__ float sme[NEXP];
    const int tid = threadIdx.x;
    const int tok0 = blockIdx.x * 32;
    const int ty = tid >> 5;
    const int tx = tid & 31;
    const int t0 = ty * 4;
    const int e0 = tx * 2;

    if (tid < NEXP) sme[tid] = 0.0f;

    float gm0 = 0.0f, gm1 = 0.0f;
#pragma unroll
    for (int i = 0; i < 4; ++i) {
        int tok = tok0 + t0 + i;
        float l0 = 0.0f, l1 = 0.0f;
#pragma unroll
        for (int s = 0; s < NSLICE; ++s) {
            float2 p = *(const float2*)&P[((size_t)s * S_TOK + tok) * NEXP + e0];
            l0 += p.x; l1 += p.y;
        }
        float v; int ix;
        if (l1 > l0) { v = l1; ix = e0 + 1; } else { v = l0; ix = e0; }
#pragma unroll
        for (int off = 16; off; off >>= 1) {
            float ov = __shfl_xor(v, off, 32);
            int   oi = __shfl_xor(ix, off, 32);
            if (ov > v || (ov == v && oi < ix)) { v = ov; ix = oi; }
        }
        float z0 = __expf(l0 - v), z1 = __expf(l1 - v);
        float zs = z0 + z1;
#pragma unroll
        for (int off = 16; off; off >>= 1) zs += __shfl_xor(zs, off, 32);
        float inv = 1.0f / zs;
        gm0 += z0 * inv; gm1 += z1 * inv;
        if (tx == 0) {
            idx_out[tok]  = ix;
            gate_out[tok] = inv;
        }
    }
    atomicAdd(&sme[e0], gm0);
    atomicAdd(&sme[e0 + 1], gm1);
    __syncthreads();
    if (tid < NEXP) atomicAdd(&gsum[tid], sme[tid]);
}

// ---------------------------------------------------------------------------
// Kernel 3: ordered per-expert rank via ballots. Builds pos2/val2 tables for
// the writer + l_aux. pos2[vt] = within-token-row offset of the hot slot
// (e*128+loc, or -1 if dropped); val2[vt] = gate (combine half) or 1.0 (mask).
// ---------------------------------------------------------------------------
__global__ __launch_bounds__(1024) void scan_kernel(
    const int* __restrict__ idx, const float* __restrict__ gate,
    const float* __restrict__ gsum,
    int* __restrict__ pos2, float* __restrict__ val2,
    float* __restrict__ laux_out)
{
    __shared__ int wavecnt[16][NEXP];
    __shared__ int basecnt[NEXP];
    const int tid  = threadIdx.x;
    const int lane = tid & 63;
    const int wv   = tid >> 6;

    if (tid < NEXP) basecnt[tid] = 0;
    __syncthreads();

    for (int it = 0; it < S_TOK / 1024; ++it) {
        int tok = it * 1024 + tid;
        int e = idx[tok];
        unsigned long long m = ~0ull, lm = ~0ull;
#pragma unroll
        for (int b = 0; b < 6; ++b) {
            unsigned long long bal = __ballot((e >> b) & 1);
            m  &= ((e >> b) & 1)    ? bal : ~bal;
            lm &= ((lane >> b) & 1) ? bal : ~bal;
        }
        int rank = __popcll(m & ((1ull << lane) - 1ull));
        wavecnt[wv][lane] = __popcll(lm);
        __syncthreads();
        int off = 0;
        for (int w = 0; w < wv; ++w) off += wavecnt[w][e];
        int loc = basecnt[e] + off + rank;
        int p = (loc < CAP) ? (e * CAP + loc) : -1;
        pos2[tok]         = p;
        pos2[tok + S_TOK] = p;
        val2[tok]         = gate[tok];
        val2[tok + S_TOK] = 1.0f;
        __syncthreads();
        if (tid < NEXP) {
            int tot = 0;
#pragma unroll
            for (int w = 0; w < 16; ++w) tot += wavecnt[w][tid];
            basecnt[tid] += tot;
        }
        __syncthreads();
    }

    if (tid < NEXP) {
        float p = gsum[tid] * (float)basecnt[tid];
#pragma unroll
        for (int off = 32; off; off >>= 1) p += __shfl_xor(p, off, 64);
        if (tid == 0) laux_out[0] = p * 9.5367431640625e-07f;  // 64/8192^2
    }
}

// ---------------------------------------------------------------------------
// Kernel 4: dense output writer. One float4 per quad m covering i=4m..4m+3,
// i.e. q = 4m-1 .. 4m+2 (q = output element - 1; out[0] is l_aux).
// A quad crosses a virtual-token boundary only when w = (4m-1)&8191 == 8191.
// grid 16384 x 256, 8 quads/thread.
// ---------------------------------------------------------------------------
__global__ __launch_bounds__(256) void writer_kernel(
    const int* __restrict__ pos2, const float* __restrict__ val2,
    const float* __restrict__ laux, float* __restrict__ out)
{
    const int tid = threadIdx.x;
    size_t m0 = (size_t)blockIdx.x * 2048 + tid;
#pragma unroll
    for (int r = 0; r < 8; ++r) {
        size_t m = m0 + 256 * (size_t)r;
        float4 v = { 0.0f, 0.0f, 0.0f, 0.0f };
        if (m == 0) {
            v.x = laux[0];
            int p = pos2[0];
            float val = val2[0];
            v.y = (p == 0) ? val : 0.0f;
            v.z = (p == 1) ? val : 0.0f;
            v.w = (p == 2) ? val : 0.0f;
        } else {
            size_t q0 = 4 * m - 1;
            int vt = (int)(q0 >> 13);
            int w  = (int)(q0 & 8191);
            int p  = pos2[vt];
            float val = val2[vt];
            if (w == 8191) {
                v.x = (p == 8191) ? val : 0.0f;
                int p2 = pos2[vt + 1];
                float val2b = val2[vt + 1];
                v.y = (p2 == 0) ? val2b : 0.0f;
                v.z = (p2 == 1) ? val2b : 0.0f;
                v.w = (p2 == 2) ? val2b : 0.0f;
            } else {
                unsigned d = (unsigned)(p - w);
                v.x = (d == 0u) ? val : 0.0f;
                v.y = (d == 1u) ? val : 0.0f;
                v.z = (d == 2u) ? val : 0.0f;
                v.w = (d == 3u) ? val : 0.0f;
            }
        }
        *(float4*)(out + 4 * m) = v;
    }
    if (blockIdx.x == 0 && tid == 0) {
        // tail element i = OUT_ELEMS-1: q = 2*COMB-1 -> vt=16383, w=8191
        out[OUT_ELEMS - 1] = (pos2[2 * S_TOK - 1] == 8191) ? 1.0f : 0.0f;
    }
}

extern "C" void kernel_launch(void* const* d_in, const int* in_sizes, int n_in,
                              void* d_out, int out_size, void* d_ws, size_t ws_size,
                              hipStream_t stream) {
    const float* x  = (const float*)d_in[0];   // [8192, 2048] fp32
    const float* wg = (const float*)d_in[1];   // [64, 2048] fp32
    float* out = (float*)d_out;

    // ws layout
    int*   idx  = (int*)d_ws;                             // 32 KB
    float* gate = (float*)((char*)d_ws + 32768);          // 32 KB
    float* gsum = (float*)((char*)d_ws + 65536);          // 256 B
    float* laux = (float*)((char*)d_ws + 65792);          // 4 B
    int*   pos2 = (int*)((char*)d_ws + 131072);           // 64 KB
    float* val2 = (float*)((char*)d_ws + 196608);         // 64 KB
    float* P    = (float*)((char*)d_ws + 262144);         // 8 MB partials

    logits_kernel<<<(S_TOK / TOK_TILE) * NSLICE, 256, 0, stream>>>(x, wg, P, gsum);
    reduce_kernel<<<S_TOK / 32, 256, 0, stream>>>(P, idx, gate, gsum);
    scan_kernel<<<1, 1024, 0, stream>>>(idx, gate, gsum, pos2, val2, laux);
    writer_kernel<<<16384, 256, 0, stream>>>(pos2, val2, laux, out);
}

// Round 4
// 615.607 us; speedup vs baseline: 1.0126x; 1.0126x over previous
//
#include <hip/hip_runtime.h>
#include <cstdint>
#include <cstddef>

// Top-1 MoE gate. s=8192, e=64, d=2048, cap=128.
// d_out (float32): [l_aux(1), combine(8192*64*128), mask(8192*64*128)]
// Pipeline:
//   fused_zero_gemm : blocks 0-255 split-K fp32 GEMM (unchanged numerics),
//                     blocks 256-1023 zero the 537MB output (overlapped pipes)
//   reduce          : 4-partial fixed-order reduce + softmax + argmax + gsum
//   scan_scatter    : ballot-ranked cumsum + capacity + sparse scatter + l_aux

#define S_TOK 8192
#define NEXP 64
#define DIM 2048
#define CAP 128
#define COMB_ELEMS ((size_t)S_TOK * NEXP * CAP)   // 67108864
#define OUT_ELEMS (1 + 2 * COMB_ELEMS)            // 134217729
#define NQUAD (OUT_ELEMS / 4)                     // 33554432 (covers 0..OUT_ELEMS-2)

#define TOK_TILE 128
#define NSLICE 4
#define KSLICE (DIM / NSLICE)   // 512
#define KC 32

#define GEMM_BLKS 256
#define ZERO_BLKS 768
#define TOTAL_BLKS (GEMM_BLKS + ZERO_BLKS)
#define QCHUNK 43691            // ceil(NQUAD / ZERO_BLKS)

// ---------------------------------------------------------------------------
// Kernel 1: fused output-zeroing + split-K logits GEMM.
// ---------------------------------------------------------------------------
__global__ __launch_bounds__(256, 4) void fused_zero_gemm(
    const float* __restrict__ x, const float* __restrict__ wg,
    float* __restrict__ P, float* __restrict__ gsum,
    float* __restrict__ out)
{
    const int tid = threadIdx.x;

    if (blockIdx.x >= GEMM_BLKS) {
        // ---- zero path: write-BW bound, overlaps GEMM blocks' compute ----
        const int zb = blockIdx.x - GEMM_BLKS;
        size_t begin = (size_t)zb * QCHUNK;
        size_t end   = begin + QCHUNK;
        if (end > (size_t)NQUAD) end = (size_t)NQUAD;
        const float4 z = { 0.0f, 0.0f, 0.0f, 0.0f };
        for (size_t q = begin + tid; q < end; q += 256)
            *(float4*)(out + 4 * q) = z;
        if (zb == 0 && tid == 0) out[OUT_ELEMS - 1] = 0.0f;  // odd tail element
        return;
    }

    // ---- GEMM path: identical numerics to R3 logits_kernel ----
    __shared__ float xs[KC][132];
    __shared__ float wsh[KC][68];

    const int tile  = blockIdx.x >> 2;
    const int slice = blockIdx.x & 3;
    const int tok0 = tile * TOK_TILE;
    const int k0   = slice * KSLICE;

    if (blockIdx.x == 0 && tid < NEXP) gsum[tid] = 0.0f;

    const int tt = tid >> 4;
    const int te = tid & 15;

    float acc[8][4];
#pragma unroll
    for (int i = 0; i < 8; ++i)
#pragma unroll
        for (int j = 0; j < 4; ++j) acc[i][j] = 0.0f;

    const int we  = tid & 63;
    const int wkq = tid >> 6;

    float4 xv[4], wv[2];
#pragma unroll
    for (int r = 0; r < 4; ++r) {
        int idx = tid + 256 * r;
        int t = idx >> 3, kq = idx & 7;
        xv[r] = *(const float4*)(x + (size_t)(tok0 + t) * DIM + k0 + 4 * kq);
    }
    wv[0] = *(const float4*)(wg + (size_t)we * DIM + k0 + 4 * wkq);
    wv[1] = *(const float4*)(wg + (size_t)we * DIM + k0 + 4 * (wkq + 4));

    for (int kc = 0; kc < KSLICE; kc += KC) {
        __syncthreads();
#pragma unroll
        for (int r = 0; r < 4; ++r) {
            int idx = tid + 256 * r;
            int t = idx >> 3, k4 = (idx & 7) * 4;
            xs[k4 + 0][t] = xv[r].x; xs[k4 + 1][t] = xv[r].y;
            xs[k4 + 2][t] = xv[r].z; xs[k4 + 3][t] = xv[r].w;
        }
        {
            int k4 = 4 * wkq;
            wsh[k4 + 0][we] = wv[0].x; wsh[k4 + 1][we] = wv[0].y;
            wsh[k4 + 2][we] = wv[0].z; wsh[k4 + 3][we] = wv[0].w;
            int k4b = k4 + 16;
            wsh[k4b + 0][we] = wv[1].x; wsh[k4b + 1][we] = wv[1].y;
            wsh[k4b + 2][we] = wv[1].z; wsh[k4b + 3][we] = wv[1].w;
        }
        __syncthreads();
        if (kc + KC < KSLICE) {
#pragma unroll
            for (int r = 0; r < 4; ++r) {
                int idx = tid + 256 * r;
                int t = idx >> 3, kq = idx & 7;
                xv[r] = *(const float4*)(x + (size_t)(tok0 + t) * DIM + k0 + kc + KC + 4 * kq);
            }
            wv[0] = *(const float4*)(wg + (size_t)we * DIM + k0 + kc + KC + 4 * wkq);
            wv[1] = *(const float4*)(wg + (size_t)we * DIM + k0 + kc + KC + 4 * (wkq + 4));
        }
#pragma unroll 8
        for (int k = 0; k < KC; ++k) {
            float4 a0 = *(const float4*)&xs[k][8 * tt];
            float4 a1 = *(const float4*)&xs[k][8 * tt + 4];
            float4 b  = *(const float4*)&wsh[k][4 * te];
            const float* ap0 = &a0.x; const float* ap1 = &a1.x; const float* bp = &b.x;
#pragma unroll
            for (int i = 0; i < 4; ++i)
#pragma unroll
                for (int j = 0; j < 4; ++j) {
                    acc[i][j]     += ap0[i] * bp[j];
                    acc[i + 4][j] += ap1[i] * bp[j];
                }
        }
    }

#pragma unroll
    for (int i = 0; i < 8; ++i) {
        size_t off = ((size_t)slice * S_TOK + tok0 + 8 * tt + i) * NEXP + 4 * te;
        float4 v = { acc[i][0], acc[i][1], acc[i][2], acc[i][3] };
        *(float4*)(P + off) = v;
    }
}

// ---------------------------------------------------------------------------
// Kernel 2: reduce 4 partials (fixed order) + softmax + argmax + gate sums.
// ---------------------------------------------------------------------------
__global__ __launch_bounds__(256) void reduce_kernel(
    const float* __restrict__ P,
    int* __restrict__ idx_out, float* __restrict__ gate_out,
    float* __restrict__ gsum)
{
    __shared__ float sme[NEXP];
    const int tid = threadIdx.x;
    const int tok0 = blockIdx.x * 32;
    const int ty = tid >> 5;
    const int tx = tid & 31;
    const int t0 = ty * 4;
    const int e0 = tx * 2;

    if (tid < NEXP) sme[tid] = 0.0f;

    float gm0 = 0.0f, gm1 = 0.0f;
#pragma unroll
    for (int i = 0; i < 4; ++i) {
        int tok = tok0 + t0 + i;
        float l0 = 0.0f, l1 = 0.0f;
#pragma unroll
        for (int s = 0; s < NSLICE; ++s) {
            float2 p = *(const float2*)&P[((size_t)s * S_TOK + tok) * NEXP + e0];
            l0 += p.x; l1 += p.y;
        }
        float v; int ix;
        if (l1 > l0) { v = l1; ix = e0 + 1; } else { v = l0; ix = e0; }
#pragma unroll
        for (int off = 16; off; off >>= 1) {
            float ov = __shfl_xor(v, off, 32);
            int   oi = __shfl_xor(ix, off, 32);
            if (ov > v || (ov == v && oi < ix)) { v = ov; ix = oi; }
        }
        float z0 = __expf(l0 - v), z1 = __expf(l1 - v);
        float zs = z0 + z1;
#pragma unroll
        for (int off = 16; off; off >>= 1) zs += __shfl_xor(zs, off, 32);
        float inv = 1.0f / zs;
        gm0 += z0 * inv; gm1 += z1 * inv;
        if (tx == 0) {
            idx_out[tok]  = ix;
            gate_out[tok] = inv;
        }
    }
    atomicAdd(&sme[e0], gm0);
    atomicAdd(&sme[e0 + 1], gm1);
    __syncthreads();
    if (tid < NEXP) atomicAdd(&gsum[tid], sme[tid]);
}

// ---------------------------------------------------------------------------
// Kernel 3: ordered per-expert rank + capacity filter + sparse scatter into
// the pre-zeroed output + l_aux. Single block, 1024 threads.
// ---------------------------------------------------------------------------
__global__ __launch_bounds__(1024) void scan_scatter(
    const int* __restrict__ idx, const float* __restrict__ gate,
    const float* __restrict__ gsum, float* __restrict__ out)
{
    __shared__ int wavecnt[16][NEXP];
    __shared__ int basecnt[NEXP];
    const int tid  = threadIdx.x;
    const int lane = tid & 63;
    const int wv   = tid >> 6;

    if (tid < NEXP) basecnt[tid] = 0;
    __syncthreads();

    for (int it = 0; it < S_TOK / 1024; ++it) {
        int tok = it * 1024 + tid;
        int e = idx[tok];
        unsigned long long m = ~0ull, lm = ~0ull;
#pragma unroll
        for (int b = 0; b < 6; ++b) {
            unsigned long long bal = __ballot((e >> b) & 1);
            m  &= ((e >> b) & 1)    ? bal : ~bal;   // lanes with my expert
            lm &= ((lane >> b) & 1) ? bal : ~bal;   // lanes with expert == lane id
        }
        int rank = __popcll(m & ((1ull << lane) - 1ull));
        wavecnt[wv][lane] = __popcll(lm);
        __syncthreads();
        int off = 0;
        for (int w = 0; w < wv; ++w) off += wavecnt[w][e];
        int loc = basecnt[e] + off + rank;
        if (loc < CAP) {
            size_t base = 1 + (size_t)tok * (NEXP * CAP) + (size_t)e * CAP + loc;
            out[base] = gate[tok];            // combine_weights
            out[base + COMB_ELEMS] = 1.0f;    // dispatch_mask
        }
        __syncthreads();
        if (tid < NEXP) {
            int tot = 0;
#pragma unroll
            for (int w = 0; w < 16; ++w) tot += wavecnt[w][tid];
            basecnt[tid] += tot;
        }
        __syncthreads();
    }

    if (tid < NEXP) {
        float p = gsum[tid] * (float)basecnt[tid];
#pragma unroll
        for (int off = 32; off; off >>= 1) p += __shfl_xor(p, off, 64);
        if (tid == 0) out[0] = p * 9.5367431640625e-07f;  // 64/8192^2
    }
}

extern "C" void kernel_launch(void* const* d_in, const int* in_sizes, int n_in,
                              void* d_out, int out_size, void* d_ws, size_t ws_size,
                              hipStream_t stream) {
    const float* x  = (const float*)d_in[0];   // [8192, 2048] fp32
    const float* wg = (const float*)d_in[1];   // [64, 2048] fp32
    float* out = (float*)d_out;

    // ws layout
    int*   idx  = (int*)d_ws;                             // 32 KB
    float* gate = (float*)((char*)d_ws + 32768);          // 32 KB
    float* gsum = (float*)((char*)d_ws + 65536);          // 256 B
    float* P    = (float*)((char*)d_ws + 262144);         // 8 MB partials

    fused_zero_gemm<<<TOTAL_BLKS, 256, 0, stream>>>(x, wg, P, gsum, out);
    reduce_kernel<<<S_TOK / 32, 256, 0, stream>>>(P, idx, gate, gsum);
    scan_scatter<<<1, 1024, 0, stream>>>(idx, gate, gsum, out);
}

// Round 5
// 591.636 us; speedup vs baseline: 1.0536x; 1.0405x over previous
//
#include <hip/hip_runtime.h>
#include <cstdint>
#include <cstddef>

// Top-1 MoE gate. s=8192, e=64, d=2048, cap=128.
// d_out (float32): [l_aux(1), combine(8192*64*128), mask(8192*64*128)]
// Pipeline (zeroing split across k1..k3 so reduce/scan hide under write BW):
//   k1 gemm_zero_a : 256 split-K GEMM blocks + 768 blocks zero region A
//   k2 reduce_zero_b: 256 reduce blocks (softmax/argmax/gsum) + 768 zero B
//   k3 scan_zero_c : block 0 ballot-rank scan (loc + l_aux) + 256 zero C
//   k4 scatter     : 2 stores per surviving token into pre-zeroed output

#define S_TOK 8192
#define NEXP 64
#define DIM 2048
#define CAP 128
#define COMB_ELEMS ((size_t)S_TOK * NEXP * CAP)   // 67108864
#define OUT_ELEMS (1 + 2 * COMB_ELEMS)            // 134217729
#define NQUAD ((size_t)(OUT_ELEMS / 4))           // 33554432 quads cover all but last elem

#define QA ((size_t)14000000)   // region A: [0, QA)          ~224 MB (k1)
#define QB ((size_t)24000000)   // region B: [QA, QB)         ~160 MB (k2)
                                // region C: [QB, NQUAD)      ~153 MB (k3)

#define TOK_TILE 128
#define NSLICE 4
#define KSLICE (DIM / NSLICE)   // 512
#define KC 32

__device__ __forceinline__ void zero_quads(float* __restrict__ out,
                                           size_t q_begin, size_t q_end,
                                           int nblocks, int bid) {
    const float4 z = { 0.0f, 0.0f, 0.0f, 0.0f };
    size_t stride = (size_t)nblocks * blockDim.x;
    for (size_t q = q_begin + (size_t)bid * blockDim.x + threadIdx.x;
         q < q_end; q += stride)
        *(float4*)(out + 4 * q) = z;
}

// ---------------------------------------------------------------------------
// Kernel 1: split-K logits GEMM (blocks 0-255) + zero region A (blocks 256-1023)
// ---------------------------------------------------------------------------
__global__ __launch_bounds__(256, 4) void gemm_zero_a(
    const float* __restrict__ x, const float* __restrict__ wg,
    float* __restrict__ P, float* __restrict__ gsum,
    float* __restrict__ out)
{
    const int tid = threadIdx.x;

    if (blockIdx.x >= 256) {
        const int zb = blockIdx.x - 256;
        zero_quads(out, 0, QA, 768, zb);
        if (zb == 0 && tid == 0) out[OUT_ELEMS - 1] = 0.0f;  // odd tail element
        return;
    }

    __shared__ float xs[KC][132];
    __shared__ float wsh[KC][68];

    const int tile  = blockIdx.x >> 2;
    const int slice = blockIdx.x & 3;
    const int tok0 = tile * TOK_TILE;
    const int k0   = slice * KSLICE;

    if (blockIdx.x == 0 && tid < NEXP) gsum[tid] = 0.0f;

    const int tt = tid >> 4;
    const int te = tid & 15;

    float acc[8][4];
#pragma unroll
    for (int i = 0; i < 8; ++i)
#pragma unroll
        for (int j = 0; j < 4; ++j) acc[i][j] = 0.0f;

    const int we  = tid & 63;
    const int wkq = tid >> 6;

    float4 xv[4], wv[2];
#pragma unroll
    for (int r = 0; r < 4; ++r) {
        int idx = tid + 256 * r;
        int t = idx >> 3, kq = idx & 7;
        xv[r] = *(const float4*)(x + (size_t)(tok0 + t) * DIM + k0 + 4 * kq);
    }
    wv[0] = *(const float4*)(wg + (size_t)we * DIM + k0 + 4 * wkq);
    wv[1] = *(const float4*)(wg + (size_t)we * DIM + k0 + 4 * (wkq + 4));

    for (int kc = 0; kc < KSLICE; kc += KC) {
        __syncthreads();
#pragma unroll
        for (int r = 0; r < 4; ++r) {
            int idx = tid + 256 * r;
            int t = idx >> 3, k4 = (idx & 7) * 4;
            xs[k4 + 0][t] = xv[r].x; xs[k4 + 1][t] = xv[r].y;
            xs[k4 + 2][t] = xv[r].z; xs[k4 + 3][t] = xv[r].w;
        }
        {
            int k4 = 4 * wkq;
            wsh[k4 + 0][we] = wv[0].x; wsh[k4 + 1][we] = wv[0].y;
            wsh[k4 + 2][we] = wv[0].z; wsh[k4 + 3][we] = wv[0].w;
            int k4b = k4 + 16;
            wsh[k4b + 0][we] = wv[1].x; wsh[k4b + 1][we] = wv[1].y;
            wsh[k4b + 2][we] = wv[1].z; wsh[k4b + 3][we] = wv[1].w;
        }
        __syncthreads();
        if (kc + KC < KSLICE) {
#pragma unroll
            for (int r = 0; r < 4; ++r) {
                int idx = tid + 256 * r;
                int t = idx >> 3, kq = idx & 7;
                xv[r] = *(const float4*)(x + (size_t)(tok0 + t) * DIM + k0 + kc + KC + 4 * kq);
            }
            wv[0] = *(const float4*)(wg + (size_t)we * DIM + k0 + kc + KC + 4 * wkq);
            wv[1] = *(const float4*)(wg + (size_t)we * DIM + k0 + kc + KC + 4 * (wkq + 4));
        }
#pragma unroll 8
        for (int k = 0; k < KC; ++k) {
            float4 a0 = *(const float4*)&xs[k][8 * tt];
            float4 a1 = *(const float4*)&xs[k][8 * tt + 4];
            float4 b  = *(const float4*)&wsh[k][4 * te];
            const float* ap0 = &a0.x; const float* ap1 = &a1.x; const float* bp = &b.x;
#pragma unroll
            for (int i = 0; i < 4; ++i)
#pragma unroll
                for (int j = 0; j < 4; ++j) {
                    acc[i][j]     += ap0[i] * bp[j];
                    acc[i + 4][j] += ap1[i] * bp[j];
                }
        }
    }

#pragma unroll
    for (int i = 0; i < 8; ++i) {
        size_t off = ((size_t)slice * S_TOK + tok0 + 8 * tt + i) * NEXP + 4 * te;
        float4 v = { acc[i][0], acc[i][1], acc[i][2], acc[i][3] };
        *(float4*)(P + off) = v;
    }
}

// ---------------------------------------------------------------------------
// Kernel 2: reduce 4 partials + softmax + argmax + gsum (blocks 0-255)
//           + zero region B (blocks 256-1023)
// ---------------------------------------------------------------------------
__global__ __launch_bounds__(256) void reduce_zero_b(
    const float* __restrict__ P,
    int* __restrict__ idx_out, float* __restrict__ gate_out,
    float* __restrict__ gsum, float* __restrict__ out)
{
    const int tid = threadIdx.x;

    if (blockIdx.x >= 256) {
        zero_quads(out, QA, QB, 768, blockIdx.x - 256);
        return;
    }

    __shared__ float sme[NEXP];
    const int tok0 = blockIdx.x * 32;
    const int ty = tid >> 5;
    const int tx = tid & 31;
    const int t0 = ty * 4;
    const int e0 = tx * 2;

    if (tid < NEXP) sme[tid] = 0.0f;

    float gm0 = 0.0f, gm1 = 0.0f;
#pragma unroll
    for (int i = 0; i < 4; ++i) {
        int tok = tok0 + t0 + i;
        float l0 = 0.0f, l1 = 0.0f;
#pragma unroll
        for (int s = 0; s < NSLICE; ++s) {
            float2 p = *(const float2*)&P[((size_t)s * S_TOK + tok) * NEXP + e0];
            l0 += p.x; l1 += p.y;
        }
        float v; int ix;
        if (l1 > l0) { v = l1; ix = e0 + 1; } else { v = l0; ix = e0; }
#pragma unroll
        for (int off = 16; off; off >>= 1) {
            float ov = __shfl_xor(v, off, 32);
            int   oi = __shfl_xor(ix, off, 32);
            if (ov > v || (ov == v && oi < ix)) { v = ov; ix = oi; }
        }
        float z0 = __expf(l0 - v), z1 = __expf(l1 - v);
        float zs = z0 + z1;
#pragma unroll
        for (int off = 16; off; off >>= 1) zs += __shfl_xor(zs, off, 32);
        float inv = 1.0f / zs;
        gm0 += z0 * inv; gm1 += z1 * inv;
        if (tx == 0) {
            idx_out[tok]  = ix;
            gate_out[tok] = inv;
        }
    }
    atomicAdd(&sme[e0], gm0);
    atomicAdd(&sme[e0 + 1], gm1);
    __syncthreads();
    if (tid < NEXP) atomicAdd(&gsum[tid], sme[tid]);
}

// ---------------------------------------------------------------------------
// Kernel 3: block 0 = ballot-rank scan -> loc[] + l_aux (out[0] is in region A,
// already zero-safe to overwrite); blocks 1-256 zero region C. 1024 threads.
// ---------------------------------------------------------------------------
__global__ __launch_bounds__(1024) void scan_zero_c(
    const int* __restrict__ idx, const float* __restrict__ gsum,
    int* __restrict__ loc_out, float* __restrict__ out)
{
    const int tid = threadIdx.x;

    if (blockIdx.x > 0) {
        zero_quads(out, QB, NQUAD, 256, (int)blockIdx.x - 1);
        return;
    }

    __shared__ int wavecnt[16][NEXP];
    __shared__ int basecnt[NEXP];
    const int lane = tid & 63;
    const int wv   = tid >> 6;

    if (tid < NEXP) basecnt[tid] = 0;
    __syncthreads();

    for (int it = 0; it < S_TOK / 1024; ++it) {
        int tok = it * 1024 + tid;
        int e = idx[tok];
        unsigned long long m = ~0ull, lm = ~0ull;
#pragma unroll
        for (int b = 0; b < 6; ++b) {
            unsigned long long bal = __ballot((e >> b) & 1);
            m  &= ((e >> b) & 1)    ? bal : ~bal;
            lm &= ((lane >> b) & 1) ? bal : ~bal;
        }
        int rank = __popcll(m & ((1ull << lane) - 1ull));
        wavecnt[wv][lane] = __popcll(lm);
        __syncthreads();
        int off = 0;
        for (int w = 0; w < wv; ++w) off += wavecnt[w][e];
        loc_out[tok] = basecnt[e] + off + rank;   // >= CAP means dropped
        __syncthreads();
        if (tid < NEXP) {
            int tot = 0;
#pragma unroll
            for (int w = 0; w < 16; ++w) tot += wavecnt[w][tid];
            basecnt[tid] += tot;
        }
        __syncthreads();
    }

    if (tid < NEXP) {
        float p = gsum[tid] * (float)basecnt[tid];
#pragma unroll
        for (int off = 32; off; off >>= 1) p += __shfl_xor(p, off, 64);
        if (tid == 0) out[0] = p * 9.5367431640625e-07f;  // 64/8192^2
    }
}

// ---------------------------------------------------------------------------
// Kernel 4: sparse scatter into fully-zeroed output. One token per thread.
// ---------------------------------------------------------------------------
__global__ __launch_bounds__(256) void scatter_kernel(
    const int* __restrict__ idx, const float* __restrict__ gate,
    const int* __restrict__ loc, float* __restrict__ out)
{
    int t = blockIdx.x * 256 + threadIdx.x;
    int l = loc[t];
    if (l < CAP) {
        size_t base = 1 + (size_t)t * (NEXP * CAP) + (size_t)idx[t] * CAP + l;
        out[base] = gate[t];              // combine_weights
        out[base + COMB_ELEMS] = 1.0f;    // dispatch_mask
    }
}

extern "C" void kernel_launch(void* const* d_in, const int* in_sizes, int n_in,
                              void* d_out, int out_size, void* d_ws, size_t ws_size,
                              hipStream_t stream) {
    const float* x  = (const float*)d_in[0];   // [8192, 2048] fp32
    const float* wg = (const float*)d_in[1];   // [64, 2048] fp32
    float* out = (float*)d_out;

    // ws layout
    int*   idx  = (int*)d_ws;                             // 32 KB
    float* gate = (float*)((char*)d_ws + 32768);          // 32 KB
    float* gsum = (float*)((char*)d_ws + 65536);          // 256 B
    int*   loc  = (int*)((char*)d_ws + 66560);            // 32 KB
    float* P    = (float*)((char*)d_ws + 262144);         // 8 MB partials

    gemm_zero_a<<<1024, 256, 0, stream>>>(x, wg, P, gsum, out);
    reduce_zero_b<<<1024, 256, 0, stream>>>(P, idx, gate, gsum, out);
    scan_zero_c<<<257, 1024, 0, stream>>>(idx, gsum, loc, out);
    scatter_kernel<<<S_TOK / 256, 256, 0, stream>>>(idx, gate, loc, out);
}